// Round 2
// baseline (506.017 us; speedup 1.0000x reference)
//
#include <hip/hip_runtime.h>
#include <hip/hip_bf16.h>

// Problem constants (fixed by the reference)
#define V 3
#define A 4
#define NN 50000
#define C 128
#define C4 32                        // C in float4 units
#define CHUNKS 128                   // row chunks per (v,a) in the column-sum kernel
#define ROWS_PER ((NN + CHUNKS - 1) / CHUNKS)   // 391
#define VA (V * A)                   // 12

__device__ __forceinline__ float dot4(float4 a, float4 b) {
    return a.x * b.x + a.y * b.y + a.z * b.z + a.w * b.w;
}

__device__ __forceinline__ float fast_tanh(float x) {
    float ax = fminf(fabsf(x), 15.f);
    float e  = __expf(2.f * ax);
    float r  = (e - 1.f) * __frcp_rn(e + 1.f);
    return copysignf(r, x);
}

// ---------------------------------------------------------------------------
// K1: partial column sums, atomic-free.
// part[chunk][va][c] = sum over this chunk's rows of x[va][n][c]
// grid = (CHUNKS, VA), block = 256
// ---------------------------------------------------------------------------
__global__ void k_colsum(const float* __restrict__ x, float* __restrict__ part) {
    const int va    = blockIdx.y;
    const int chunk = blockIdx.x;
    const int n0 = chunk * ROWS_PER;
    const int n1 = (n0 + ROWS_PER < NN) ? (n0 + ROWS_PER) : NN;

    const int lane4 = threadIdx.x & 31;   // float4 index within the row
    const int rowIn = threadIdx.x >> 5;   // 0..7

    const float4* xp = (const float4*)(x + (size_t)va * NN * C);
    float4 acc = {0.f, 0.f, 0.f, 0.f};
    for (int n = n0 + rowIn; n < n1; n += 8) {
        float4 v = xp[(size_t)n * C4 + lane4];
        acc.x += v.x; acc.y += v.y; acc.z += v.z; acc.w += v.w;
    }

    __shared__ float4 red[256];
    red[threadIdx.x] = acc;
    __syncthreads();
    if (threadIdx.x < 32) {
        float4 t = red[threadIdx.x];
        #pragma unroll
        for (int r = 1; r < 8; r++) {
            float4 o = red[threadIdx.x + 32 * r];
            t.x += o.x; t.y += o.y; t.z += o.z; t.w += o.w;
        }
        ((float4*)part)[((size_t)chunk * VA + va) * C4 + lane4] = t;
    }
}

// ---------------------------------------------------------------------------
// K2: reduce partials -> sbar; t[va,c] = sum_d sbar[d] * W[v,d,c]; c0 = sbar.b
// grid = VA blocks, block = 128
// ---------------------------------------------------------------------------
__global__ void k_tvec(const float* __restrict__ part, const float* __restrict__ W,
                       const float* __restrict__ b, float* __restrict__ t,
                       float* __restrict__ c0) {
    const int va = blockIdx.x;       // 0..11
    const int v  = va / A;
    const int c  = threadIdx.x;      // 0..127

    float acc = 0.f;
    #pragma unroll 4
    for (int ch = 0; ch < CHUNKS; ch++)
        acc += part[((size_t)ch * VA + va) * C + c];

    __shared__ float sb[C];
    __shared__ float pb[C];
    sb[c] = acc * (1.0f / (float)NN);
    __syncthreads();

    const float* Wv = W + (size_t)v * C * C;
    float t_acc = 0.f;
    #pragma unroll 8
    for (int d = 0; d < C; d++) t_acc += sb[d] * Wv[d * C + c];
    t[va * C + c] = t_acc;

    pb[c] = sb[c] * b[v * C + c];
    __syncthreads();
    #pragma unroll
    for (int s = 64; s > 0; s >>= 1) {
        if (c < s) pb[c] += pb[c + s];
        __syncthreads();
    }
    if (c == 0) c0[va] = pb[0];
}

// ---------------------------------------------------------------------------
// K3: fused scores -> tanh -> softmax over V -> weighted combine.
// One 32-lane group handles TWO consecutive nodes (more MLP).
// grid = (NN/16, A), block = 256 (8 groups x 2 nodes = 16 nodes/block)
// ---------------------------------------------------------------------------
__global__ void k_main(const float* __restrict__ x, const float* __restrict__ t,
                       const float* __restrict__ c0, float* __restrict__ out) {
    const int lane = threadIdx.x & 31;
    const int grp  = threadIdx.x >> 5;            // 0..7
    const int a    = blockIdx.y;
    const int n0   = blockIdx.x * 16 + grp * 2;   // nodes n0 and n0+1

    const size_t vstride = (size_t)A * NN * C4;   // view stride in float4 units
    const float4* xp = (const float4*)x;
    const size_t baseA = ((size_t)a * NN + n0) * C4 + lane;
    const size_t baseB = baseA + C4;

    // 6 independent 16B loads per thread
    float4 xa0 = xp[baseA];
    float4 xa1 = xp[baseA + vstride];
    float4 xa2 = xp[baseA + 2 * vstride];
    float4 xb0 = xp[baseB];
    float4 xb1 = xp[baseB + vstride];
    float4 xb2 = xp[baseB + 2 * vstride];

    const float4* tp = (const float4*)t;
    float4 t0 = tp[(0 * A + a) * C4 + lane];
    float4 t1 = tp[(1 * A + a) * C4 + lane];
    float4 t2 = tp[(2 * A + a) * C4 + lane];

    float da0 = dot4(xa0, t0), da1 = dot4(xa1, t1), da2 = dot4(xa2, t2);
    float db0 = dot4(xb0, t0), db1 = dot4(xb1, t1), db2 = dot4(xb2, t2);

    #pragma unroll
    for (int off = 16; off > 0; off >>= 1) {
        da0 += __shfl_xor(da0, off, 32);
        da1 += __shfl_xor(da1, off, 32);
        da2 += __shfl_xor(da2, off, 32);
        db0 += __shfl_xor(db0, off, 32);
        db1 += __shfl_xor(db1, off, 32);
        db2 += __shfl_xor(db2, off, 32);
    }

    const float cc0 = c0[0 * A + a], cc1 = c0[1 * A + a], cc2 = c0[2 * A + a];

    // node A weights
    float sa0 = fast_tanh(da0 + cc0);
    float sa1 = fast_tanh(da1 + cc1);
    float sa2 = fast_tanh(da2 + cc2);
    float ma  = fmaxf(sa0, fmaxf(sa1, sa2));
    float ea0 = __expf(sa0 - ma), ea1 = __expf(sa1 - ma), ea2 = __expf(sa2 - ma);
    float inva = __frcp_rn(ea0 + ea1 + ea2);
    float wa0 = ea0 * inva, wa1 = ea1 * inva, wa2 = ea2 * inva;

    // node B weights
    float sb0 = fast_tanh(db0 + cc0);
    float sb1 = fast_tanh(db1 + cc1);
    float sb2 = fast_tanh(db2 + cc2);
    float mb  = fmaxf(sb0, fmaxf(sb1, sb2));
    float eb0 = __expf(sb0 - mb), eb1 = __expf(sb1 - mb), eb2 = __expf(sb2 - mb);
    float invb = __frcp_rn(eb0 + eb1 + eb2);
    float wb0 = eb0 * invb, wb1 = eb1 * invb, wb2 = eb2 * invb;

    float4 oa, ob;
    oa.x = wa0 * xa0.x + wa1 * xa1.x + wa2 * xa2.x;
    oa.y = wa0 * xa0.y + wa1 * xa1.y + wa2 * xa2.y;
    oa.z = wa0 * xa0.z + wa1 * xa1.z + wa2 * xa2.z;
    oa.w = wa0 * xa0.w + wa1 * xa1.w + wa2 * xa2.w;
    ob.x = wb0 * xb0.x + wb1 * xb1.x + wb2 * xb2.x;
    ob.y = wb0 * xb0.y + wb1 * xb1.y + wb2 * xb2.y;
    ob.z = wb0 * xb0.z + wb1 * xb1.z + wb2 * xb2.z;
    ob.w = wb0 * xb0.w + wb1 * xb1.w + wb2 * xb2.w;

    float4* op = (float4*)out;
    const size_t obase = ((size_t)a * NN + n0) * C4 + lane;
    op[obase]      = oa;
    op[obase + C4] = ob;
}

// ---------------------------------------------------------------------------
extern "C" void kernel_launch(void* const* d_in, const int* in_sizes, int n_in,
                              void* d_out, int out_size, void* d_ws, size_t ws_size,
                              hipStream_t stream) {
    const float* x = (const float*)d_in[0];
    const float* W = (const float*)d_in[1];
    const float* b = (const float*)d_in[2];
    float* out = (float*)d_out;

    float* part = (float*)d_ws;                   // CHUNKS*VA*C floats (~786 KB)
    float* t    = part + (size_t)CHUNKS * VA * C; // VA*C floats
    float* c0   = t + VA * C;                     // VA floats

    k_colsum<<<dim3(CHUNKS, VA), 256, 0, stream>>>(x, part);
    k_tvec<<<VA, C, 0, stream>>>(part, W, b, t, c0);
    k_main<<<dim3(NN / 16, A), 256, 0, stream>>>(x, t, c0, out);
}

// Round 4
// 489.806 us; speedup vs baseline: 1.0331x; 1.0331x over previous
//
#include <hip/hip_runtime.h>
#include <hip/hip_bf16.h>

// Problem constants (fixed by the reference)
#define V 3
#define A 4
#define NN 50000
#define C 128
#define C4 32                        // C in float4 units
#define CHUNKS 128                   // row chunks per (v,a) in the column-sum kernel
#define ROWS_PER ((NN + CHUNKS - 1) / CHUNKS)   // 391
#define VA (V * A)                   // 12

typedef float nf4 __attribute__((ext_vector_type(4)));  // native vec4 for nontemporal store

__device__ __forceinline__ float dot4(float4 a, float4 b) {
    return a.x * b.x + a.y * b.y + a.z * b.z + a.w * b.w;
}

__device__ __forceinline__ float fast_tanh(float x) {
    float ax = fminf(fabsf(x), 15.f);
    float e  = __expf(2.f * ax);
    float r  = (e - 1.f) * __frcp_rn(e + 1.f);
    return copysignf(r, x);
}

// ---------------------------------------------------------------------------
// K1: partial column sums, atomic-free.
// part[chunk][va][c] = sum over this chunk's rows of x[va][n][c]
// grid = (CHUNKS, VA), block = 256.  Streams all of x (307 MB) into L3.
// ---------------------------------------------------------------------------
__global__ void k_colsum(const float* __restrict__ x, float* __restrict__ part) {
    const int va    = blockIdx.y;
    const int chunk = blockIdx.x;
    const int n0 = chunk * ROWS_PER;
    const int n1 = (n0 + ROWS_PER < NN) ? (n0 + ROWS_PER) : NN;

    const int lane4 = threadIdx.x & 31;   // float4 index within the row
    const int rowIn = threadIdx.x >> 5;   // 0..7

    const float4* xp = (const float4*)(x + (size_t)va * NN * C);
    float4 acc = {0.f, 0.f, 0.f, 0.f};
    #pragma unroll 4
    for (int n = n0 + rowIn; n < n1; n += 8) {
        float4 v = xp[(size_t)n * C4 + lane4];
        acc.x += v.x; acc.y += v.y; acc.z += v.z; acc.w += v.w;
    }

    __shared__ float4 red[256];
    red[threadIdx.x] = acc;
    __syncthreads();
    if (threadIdx.x < 32) {
        float4 t = red[threadIdx.x];
        #pragma unroll
        for (int r = 1; r < 8; r++) {
            float4 o = red[threadIdx.x + 32 * r];
            t.x += o.x; t.y += o.y; t.z += o.z; t.w += o.w;
        }
        ((float4*)part)[((size_t)chunk * VA + va) * C4 + lane4] = t;
    }
}

// ---------------------------------------------------------------------------
// K2: reduce partials -> sbar; t[va,c] = sum_d sbar[d]*W[v,d,c]; c0 = sbar.b
// grid = VA blocks, block = 256 (split-K across thread halves for latency).
// ---------------------------------------------------------------------------
__global__ void k_tvec(const float* __restrict__ part, const float* __restrict__ W,
                       const float* __restrict__ b, float* __restrict__ t,
                       float* __restrict__ c0) {
    const int va   = blockIdx.x;        // 0..11
    const int v    = va / A;
    const int c    = threadIdx.x & 127; // 0..127
    const int half = threadIdx.x >> 7;  // 0 or 1

    // --- chunk reduction, split across the two halves (64 chunks each) ---
    float acc = 0.f;
    #pragma unroll 8
    for (int ch = half * 64; ch < half * 64 + 64; ch++)
        acc += part[((size_t)ch * VA + va) * C + c];

    __shared__ float red[2][C];
    __shared__ float sb[C];
    __shared__ float pb[C];
    red[half][c] = acc;
    __syncthreads();
    if (threadIdx.x < C)
        sb[c] = (red[0][c] + red[1][c]) * (1.0f / (float)NN);
    __syncthreads();

    // --- t[va,c] = sum_d sb[d] * W[v,d,c], split-K over the two halves ---
    const float* Wv = W + (size_t)v * C * C;
    float t_acc = 0.f;
    #pragma unroll 8
    for (int d = half * 64; d < half * 64 + 64; d++)
        t_acc += sb[d] * Wv[d * C + c];
    red[half][c] = t_acc;
    __syncthreads();
    if (threadIdx.x < C) {
        t[va * C + c] = red[0][c] + red[1][c];
        pb[c] = sb[c] * b[v * C + c];
    }
    __syncthreads();
    #pragma unroll
    for (int s = 64; s > 0; s >>= 1) {
        if (threadIdx.x < s) pb[threadIdx.x] += pb[threadIdx.x + s];
        __syncthreads();
    }
    if (threadIdx.x == 0) c0[va] = pb[0];
}

// ---------------------------------------------------------------------------
// K3: fused scores -> tanh -> softmax over V -> weighted combine.
// One 32-lane group handles TWO consecutive nodes. Nodes are visited in
// REVERSE order so the first-dispatched blocks touch the x lines k_colsum
// streamed last (still L3-resident). Output stores are nontemporal so the
// 102 MB of writes don't evict x from L3 mid-pass.
// grid = (NN/16, A), block = 256 (8 groups x 2 nodes = 16 nodes/block)
// ---------------------------------------------------------------------------
__global__ void k_main(const float* __restrict__ x, const float* __restrict__ t,
                       const float* __restrict__ c0, float* __restrict__ out) {
    const int lane = threadIdx.x & 31;
    const int grp  = threadIdx.x >> 5;            // 0..7
    const int a    = blockIdx.y;
    // reverse mapping: bx=0 -> last 16 nodes (most recently cached by colsum)
    const int n0   = (NN - 16) - blockIdx.x * 16 + grp * 2;

    const size_t vstride = (size_t)A * NN * C4;   // view stride in float4 units
    const float4* xp = (const float4*)x;
    const size_t baseA = ((size_t)a * NN + n0) * C4 + lane;
    const size_t baseB = baseA + C4;

    // 6 independent 16B loads per thread
    float4 xa0 = xp[baseA];
    float4 xa1 = xp[baseA + vstride];
    float4 xa2 = xp[baseA + 2 * vstride];
    float4 xb0 = xp[baseB];
    float4 xb1 = xp[baseB + vstride];
    float4 xb2 = xp[baseB + 2 * vstride];

    const float4* tp = (const float4*)t;
    float4 t0 = tp[(0 * A + a) * C4 + lane];
    float4 t1 = tp[(1 * A + a) * C4 + lane];
    float4 t2 = tp[(2 * A + a) * C4 + lane];

    float da0 = dot4(xa0, t0), da1 = dot4(xa1, t1), da2 = dot4(xa2, t2);
    float db0 = dot4(xb0, t0), db1 = dot4(xb1, t1), db2 = dot4(xb2, t2);

    #pragma unroll
    for (int off = 16; off > 0; off >>= 1) {
        da0 += __shfl_xor(da0, off, 32);
        da1 += __shfl_xor(da1, off, 32);
        da2 += __shfl_xor(da2, off, 32);
        db0 += __shfl_xor(db0, off, 32);
        db1 += __shfl_xor(db1, off, 32);
        db2 += __shfl_xor(db2, off, 32);
    }

    const float cc0 = c0[0 * A + a], cc1 = c0[1 * A + a], cc2 = c0[2 * A + a];

    // node A weights
    float sa0 = fast_tanh(da0 + cc0);
    float sa1 = fast_tanh(da1 + cc1);
    float sa2 = fast_tanh(da2 + cc2);
    float ma  = fmaxf(sa0, fmaxf(sa1, sa2));
    float ea0 = __expf(sa0 - ma), ea1 = __expf(sa1 - ma), ea2 = __expf(sa2 - ma);
    float inva = __frcp_rn(ea0 + ea1 + ea2);
    float wa0 = ea0 * inva, wa1 = ea1 * inva, wa2 = ea2 * inva;

    // node B weights
    float sb0 = fast_tanh(db0 + cc0);
    float sb1 = fast_tanh(db1 + cc1);
    float sb2 = fast_tanh(db2 + cc2);
    float mb  = fmaxf(sb0, fmaxf(sb1, sb2));
    float eb0 = __expf(sb0 - mb), eb1 = __expf(sb1 - mb), eb2 = __expf(sb2 - mb);
    float invb = __frcp_rn(eb0 + eb1 + eb2);
    float wb0 = eb0 * invb, wb1 = eb1 * invb, wb2 = eb2 * invb;

    nf4 oa, ob;
    oa.x = wa0 * xa0.x + wa1 * xa1.x + wa2 * xa2.x;
    oa.y = wa0 * xa0.y + wa1 * xa1.y + wa2 * xa2.y;
    oa.z = wa0 * xa0.z + wa1 * xa1.z + wa2 * xa2.z;
    oa.w = wa0 * xa0.w + wa1 * xa1.w + wa2 * xa2.w;
    ob.x = wb0 * xb0.x + wb1 * xb1.x + wb2 * xb2.x;
    ob.y = wb0 * xb0.y + wb1 * xb1.y + wb2 * xb2.y;
    ob.z = wb0 * xb0.z + wb1 * xb1.z + wb2 * xb2.z;
    ob.w = wb0 * xb0.w + wb1 * xb1.w + wb2 * xb2.w;

    nf4* op = (nf4*)out;
    const size_t obase = ((size_t)a * NN + n0) * C4 + lane;
    __builtin_nontemporal_store(oa, op + obase);
    __builtin_nontemporal_store(ob, op + obase + C4);
}

// ---------------------------------------------------------------------------
extern "C" void kernel_launch(void* const* d_in, const int* in_sizes, int n_in,
                              void* d_out, int out_size, void* d_ws, size_t ws_size,
                              hipStream_t stream) {
    const float* x = (const float*)d_in[0];
    const float* W = (const float*)d_in[1];
    const float* b = (const float*)d_in[2];
    float* out = (float*)d_out;

    float* part = (float*)d_ws;                   // CHUNKS*VA*C floats (~786 KB)
    float* t    = part + (size_t)CHUNKS * VA * C; // VA*C floats
    float* c0   = t + VA * C;                     // VA floats

    k_colsum<<<dim3(CHUNKS, VA), 256, 0, stream>>>(x, part);
    k_tvec<<<VA, 256, 0, stream>>>(part, W, b, t, c0);
    k_main<<<dim3(NN / 16, A), 256, 0, stream>>>(x, t, c0, out);
}